// Round 1
// baseline (889.544 us; speedup 1.0000x reference)
//
#include <hip/hip_runtime.h>
#include <hip/hip_bf16.h>
#include <cstdint>

// FlipLinear: out[M,N] = x[M,K] @ W[N,K]^T, W = ternary * scales[group],
// group = 128 contiguous K elements of row-major [N,K] => group id = n*32 + k/128.
// M=8192, N=4096, K=4096.
//
// Strategy: bf16 MFMA with EXACT ternary operand; x split into bf16 hi+lo
// (hi = bit-truncation, exact; lo = residual) => per-term error ~2^-16.
// Per-group fp32 scale applied to per-group MFMA partial sums (group = 2 K-tiles).

using bf16x8 = __attribute__((ext_vector_type(8))) __bf16;
using f32x4  = __attribute__((ext_vector_type(4))) float;
using i32x4  = __attribute__((ext_vector_type(4))) int;
using u16x8  = __attribute__((ext_vector_type(8))) unsigned short;

constexpr int M_DIM = 8192;
constexpr int N_DIM = 4096;
constexpr int K_DIM = 4096;
constexpr int BM = 128, BN = 128, BK = 64;
constexpr int GRID_N = N_DIM / BN;  // 32
constexpr int GRID_M = M_DIM / BM;  // 64

__global__ __launch_bounds__(256, 2)
void flip_gemm(const float* __restrict__ x, const int* __restrict__ tern,
               const float* __restrict__ scales, float* __restrict__ out) {
  // 48 KiB LDS, single-buffered 2-barrier loop.
  __shared__ __align__(16) unsigned short sAhi[BM * BK];
  __shared__ __align__(16) unsigned short sAlo[BM * BK];
  __shared__ __align__(16) unsigned short sB [BN * BK];

  const int t    = threadIdx.x;          // 0..255
  const int bid  = blockIdx.x;
  const int bn   = bid & (GRID_N - 1);   // neighbor blocks share A row-panel in L2/L3
  const int bm   = bid >> 5;
  const int rowBase = bm * BM;
  const int colBase = bn * BN;

  const int wid  = t >> 6;
  const int lane = t & 63;
  const int wr   = wid >> 1;             // 2x2 wave grid, each wave 64x64
  const int wc   = wid & 1;
  const int lr   = lane & 15;
  const int lk   = lane >> 4;            // 0..3

  f32x4 acc[4][4];
  f32x4 gacc[4][4];
#pragma unroll
  for (int m = 0; m < 4; ++m)
#pragma unroll
    for (int n = 0; n < 4; ++n) {
      acc[m][n]  = f32x4{0.f, 0.f, 0.f, 0.f};
      gacc[m][n] = f32x4{0.f, 0.f, 0.f, 0.f};
    }

  float sreg[4];  // per-group scales, prefetched at even kt, applied after odd kt

  for (int kt = 0; kt < K_DIM / BK; ++kt) {
    const int k0 = kt * BK;

    // ---------------- stage: global -> regs (convert) -> LDS (swizzled) ------
    // 1024 16B-chunks per tile (128 rows x 8 chunks); thread handles 4.
#pragma unroll
    for (int i = 0; i < 4; ++i) {
      const int chunk = i * 256 + t;
      const int r  = chunk >> 3;         // row in tile
      const int c  = chunk & 7;          // 16B chunk within row (8 bf16)
      const int sw = ((c ^ (r & 7)) * 8); // T2 XOR swizzle (both sides)

      // A: 8 consecutive fp32 -> hi/lo bf16
      const f32x4* asrc = reinterpret_cast<const f32x4*>(
          x + (size_t)(rowBase + r) * K_DIM + k0 + c * 8);
      f32x4 f0 = asrc[0], f1 = asrc[1];
      u16x8 hv, lv;
#pragma unroll
      for (int j = 0; j < 8; ++j) {
        float f = (j < 4) ? f0[j] : f1[j - 4];
        unsigned u  = __builtin_bit_cast(unsigned, f);
        unsigned hb = u & 0xffff0000u;               // truncated hi: exact bf16
        float flo   = f - __builtin_bit_cast(float, hb);
        unsigned lb = __builtin_bit_cast(unsigned, flo);
        hv[j] = (unsigned short)(hb >> 16);
        lv[j] = (unsigned short)(lb >> 16);          // truncate lo: err ~2^-16 rel
      }
      *reinterpret_cast<u16x8*>(&sAhi[r * BK + sw]) = hv;
      *reinterpret_cast<u16x8*>(&sAlo[r * BK + sw]) = lv;

      // B: 8 consecutive int32 in {-1,0,1} -> exact bf16 bits
      const i32x4* bsrc = reinterpret_cast<const i32x4*>(
          tern + (size_t)(colBase + r) * K_DIM + k0 + c * 8);
      i32x4 b0 = bsrc[0], b1 = bsrc[1];
      u16x8 bv;
#pragma unroll
      for (int j = 0; j < 8; ++j) {
        int v = (j < 4) ? b0[j] : b1[j - 4];
        unsigned bits = ((v & 1) ? 0x3F80u : 0u) | (((unsigned)(v >> 16)) & 0x8000u);
        bv[j] = (unsigned short)bits;
      }
      *reinterpret_cast<u16x8*>(&sB[r * BK + sw]) = bv;
    }

    // prefetch scales for group g = kt/2 (one scalar per n-frag; col fixed per lane)
    if (!(kt & 1)) {
      const int g = kt >> 1;
#pragma unroll
      for (int n = 0; n < 4; ++n) {
        const int col = colBase + wc * 64 + n * 16 + lr;
        sreg[n] = scales[col * 32 + g];
      }
    }

    __syncthreads();

    // ---------------- compute: 2 k-steps x 4m x 4n x {hi,lo} MFMAs -----------
#pragma unroll
    for (int ks = 0; ks < 2; ++ks) {
      bf16x8 bfr[4], ah[4], al[4];
#pragma unroll
      for (int n = 0; n < 4; ++n) {
        const int row   = wc * 64 + n * 16 + lr;
        const int chunk = ks * 4 + lk;
        const int addr  = row * BK + ((chunk ^ (row & 7)) * 8);
        bfr[n] = *reinterpret_cast<const bf16x8*>(&sB[addr]);
      }
#pragma unroll
      for (int m = 0; m < 4; ++m) {
        const int row   = wr * 64 + m * 16 + lr;
        const int chunk = ks * 4 + lk;
        const int addr  = row * BK + ((chunk ^ (row & 7)) * 8);
        ah[m] = *reinterpret_cast<const bf16x8*>(&sAhi[addr]);
        al[m] = *reinterpret_cast<const bf16x8*>(&sAlo[addr]);
      }
#pragma unroll
      for (int m = 0; m < 4; ++m)
#pragma unroll
        for (int n = 0; n < 4; ++n) {
          gacc[m][n] = __builtin_amdgcn_mfma_f32_16x16x32_bf16(ah[m], bfr[n], gacc[m][n], 0, 0, 0);
          gacc[m][n] = __builtin_amdgcn_mfma_f32_16x16x32_bf16(al[m], bfr[n], gacc[m][n], 0, 0, 0);
        }
    }

    // group boundary every 2 K-tiles: fold group partials with fp32 scale
    if (kt & 1) {
#pragma unroll
      for (int m = 0; m < 4; ++m)
#pragma unroll
        for (int n = 0; n < 4; ++n) {
          acc[m][n] += gacc[m][n] * sreg[n];
          gacc[m][n] = f32x4{0.f, 0.f, 0.f, 0.f};
        }
    }

    __syncthreads();
  }

  // ---------------- epilogue: C layout col=lane&15, row=(lane>>4)*4+j --------
#pragma unroll
  for (int m = 0; m < 4; ++m)
#pragma unroll
    for (int n = 0; n < 4; ++n) {
      const int col = colBase + wc * 64 + n * 16 + lr;
#pragma unroll
      for (int j = 0; j < 4; ++j) {
        const int row = rowBase + wr * 64 + m * 16 + lk * 4 + j;
        out[(size_t)row * N_DIM + col] = acc[m][n][j];
      }
    }
}

extern "C" void kernel_launch(void* const* d_in, const int* in_sizes, int n_in,
                              void* d_out, int out_size, void* d_ws, size_t ws_size,
                              hipStream_t stream) {
  const float* x      = (const float*)d_in[0];
  const int*   tern   = (const int*)d_in[1];
  const float* scales = (const float*)d_in[2];
  float* out          = (float*)d_out;

  dim3 grid(GRID_M * GRID_N);  // 2048 blocks; bid%32 = N-block -> A panel L2 reuse
  dim3 block(256);
  flip_gemm<<<grid, block, 0, stream>>>(x, tern, scales, out);
}

// Round 4
// 515.166 us; speedup vs baseline: 1.7267x; 1.7267x over previous
//
#include <hip/hip_runtime.h>
#include <hip/hip_bf16.h>
#include <hip/hip_fp16.h>
#include <cstdint>

// FlipLinear: out[M,N] = x[M,K] @ W[N,K]^T, W = ternary * scales[group],
// group = 128 contiguous K elems of row-major [N,K].  M=8192, N=4096, K=4096.
//
// R2 scheme: single-pass FP16 MFMA.
//   - W_h = fp16(ternary * scale)  (rel err 2^-12; scales in [0.005,0.05], no subnormals)
//   - x_h = fp16(x)                (rel err 2^-12; |x| <~ 6, no overflow)
//   - output err ~3e-4 std, ~2e-3 max  << reference bf16 grain (absmax 0.03125 observed)
// Precompute both into d_ws once per launch (harness re-poisons ws every call),
// then run an m97-structure 128x128 GEMM: global_load_lds(16B) staging with
// inverse-swizzled per-lane global source + XOR-swizzled ds_read_b128 (T2, rule 21).

using f16x8  = __attribute__((ext_vector_type(8))) _Float16;
using f32x4  = __attribute__((ext_vector_type(4))) float;
using i32x4  = __attribute__((ext_vector_type(4))) int;
using bf16x8 = __attribute__((ext_vector_type(8))) __bf16;
using u16x8  = __attribute__((ext_vector_type(8))) unsigned short;

constexpr int M_DIM = 8192;
constexpr int N_DIM = 4096;
constexpr int K_DIM = 4096;
constexpr int BM = 128, BN = 128, BK = 64;
constexpr int GRID_N = N_DIM / BN;  // 32
constexpr int GRID_M = M_DIM / BM;  // 64

constexpr size_t XH_ELEMS = (size_t)M_DIM * K_DIM;            // 33,554,432
constexpr size_t WH_ELEMS = (size_t)N_DIM * K_DIM;            // 16,777,216
constexpr size_t WS_NEED  = (XH_ELEMS + WH_ELEMS) * 2;        // 100,663,296 B

// ---------------------------------------------------------------- precompute
__global__ __launch_bounds__(256)
void xcvt(const float* __restrict__ x, _Float16* __restrict__ xh) {
  const size_t idx = (size_t)blockIdx.x * 256 + threadIdx.x;  // 8 elems/thread
  const f32x4* src = reinterpret_cast<const f32x4*>(x) + idx * 2;
  f32x4 a = src[0], b = src[1];
  f16x8 h;
#pragma unroll
  for (int j = 0; j < 8; ++j) h[j] = (_Float16)((j < 4) ? a[j] : b[j - 4]);
  reinterpret_cast<f16x8*>(xh)[idx] = h;
}

__global__ __launch_bounds__(256)
void wcvt(const int* __restrict__ tern, const float* __restrict__ scales,
          _Float16* __restrict__ wh) {
  const size_t idx = (size_t)blockIdx.x * 256 + threadIdx.x;  // 8 elems/thread
  const float s = scales[idx >> 4];  // flat group = (idx*8)/128
  const i32x4* src = reinterpret_cast<const i32x4*>(tern) + idx * 2;
  i32x4 a = src[0], b = src[1];
  f16x8 h;
#pragma unroll
  for (int j = 0; j < 8; ++j) {
    int v = (j < 4) ? a[j] : b[j - 4];
    h[j] = (_Float16)(s * (float)v);
  }
  reinterpret_cast<f16x8*>(wh)[idx] = h;
}

// ---------------------------------------------------------------- main GEMM
__global__ __launch_bounds__(256, 3)
void flip_gemm_f16(const _Float16* __restrict__ xh, const _Float16* __restrict__ wh,
                   float* __restrict__ out) {
  // 32 KiB LDS, single-buffered 2-barrier loop (m97 structure).
  // LDS logical layout: chunk p in [0,1024), p = r*8 + cpos (16B chunks).
  // LDS chunk (r,cpos) holds global chunk (r, cpos ^ (r&7))  [XOR involution].
  __shared__ __align__(16) _Float16 sA[BM * BK];
  __shared__ __align__(16) _Float16 sB[BN * BK];

  const int t    = threadIdx.x;
  const int bid  = blockIdx.x;
  const int bn   = bid & (GRID_N - 1);   // consecutive bids share the A panel
  const int bm   = bid >> 5;
  const int rowBase = bm * BM;
  const int colBase = bn * BN;

  const int wid  = t >> 6;
  const int lane = t & 63;
  const int wr   = wid >> 1;             // 2x2 waves, each 64x64 output
  const int wc   = wid & 1;
  const int lr   = lane & 15;
  const int lk   = lane >> 4;            // 0..3

  f32x4 acc[4][4];
#pragma unroll
  for (int m = 0; m < 4; ++m)
#pragma unroll
    for (int n = 0; n < 4; ++n) acc[m][n] = f32x4{0.f, 0.f, 0.f, 0.f};

  for (int kt = 0; kt < K_DIM / BK; ++kt) {
    const int k0 = kt * BK;

    // stage: 1024 chunks/tile, 4 waves -> 4 global_load_lds per wave per tile.
    // dest LDS is linear (base + lane*16); source address carries the inverse swizzle.
#pragma unroll
    for (int i = 0; i < 4; ++i) {
      const int c0   = wid * 256 + i * 64;       // wave-uniform base chunk
      const int p    = c0 + lane;
      const int r    = p >> 3;
      const int cpos = p & 7;
      const int ck   = cpos ^ (r & 7);
      const _Float16* ga = xh + (size_t)(rowBase + r) * K_DIM + k0 + ck * 8;
      const _Float16* gb = wh + (size_t)(colBase + r) * K_DIM + k0 + ck * 8;
      __builtin_amdgcn_global_load_lds(
          (const __attribute__((address_space(1))) unsigned int*)ga,
          (__attribute__((address_space(3))) unsigned int*)(&sA[c0 * 8]), 16, 0, 0);
      __builtin_amdgcn_global_load_lds(
          (const __attribute__((address_space(1))) unsigned int*)gb,
          (__attribute__((address_space(3))) unsigned int*)(&sB[c0 * 8]), 16, 0, 0);
    }

    __syncthreads();

#pragma unroll
    for (int ks = 0; ks < 2; ++ks) {
      f16x8 bfr[4], afr[4];
#pragma unroll
      for (int n = 0; n < 4; ++n) {
        const int row  = wc * 64 + n * 16 + lr;
        const int cpos = (ks * 4 + lk) ^ (row & 7);
        bfr[n] = *reinterpret_cast<const f16x8*>(&sB[row * BK + cpos * 8]);
      }
#pragma unroll
      for (int m = 0; m < 4; ++m) {
        const int row  = wr * 64 + m * 16 + lr;
        const int cpos = (ks * 4 + lk) ^ (row & 7);
        afr[m] = *reinterpret_cast<const f16x8*>(&sA[row * BK + cpos * 8]);
      }
#pragma unroll
      for (int m = 0; m < 4; ++m)
#pragma unroll
        for (int n = 0; n < 4; ++n)
          acc[m][n] = __builtin_amdgcn_mfma_f32_16x16x32_f16(afr[m], bfr[n], acc[m][n], 0, 0, 0);
    }

    __syncthreads();
  }

  // epilogue: C layout col=lane&15, row=(lane>>4)*4+j  (verified in R1)
#pragma unroll
  for (int m = 0; m < 4; ++m)
#pragma unroll
    for (int n = 0; n < 4; ++n) {
      const int col = colBase + wc * 64 + n * 16 + lr;
#pragma unroll
      for (int j = 0; j < 4; ++j) {
        const int row = rowBase + wr * 64 + m * 16 + lk * 4 + j;
        out[(size_t)row * N_DIM + col] = acc[m][n][j];
      }
    }
}

// ---------------------------------------------------------------- fallback (R1 kernel, known-passing)
__global__ __launch_bounds__(256, 2)
void flip_gemm_fb(const float* __restrict__ x, const int* __restrict__ tern,
                  const float* __restrict__ scales, float* __restrict__ out) {
  __shared__ __align__(16) unsigned short sAhi[BM * BK];
  __shared__ __align__(16) unsigned short sAlo[BM * BK];
  __shared__ __align__(16) unsigned short sB [BM * BK];

  const int t = threadIdx.x, bid = blockIdx.x;
  const int bn = bid & (GRID_N - 1), bm = bid >> 5;
  const int rowBase = bm * BM, colBase = bn * BN;
  const int wid = t >> 6, lane = t & 63;
  const int wr = wid >> 1, wc = wid & 1, lr = lane & 15, lk = lane >> 4;

  f32x4 acc[4][4], gacc[4][4];
#pragma unroll
  for (int m = 0; m < 4; ++m)
#pragma unroll
    for (int n = 0; n < 4; ++n) {
      acc[m][n] = f32x4{0.f, 0.f, 0.f, 0.f};
      gacc[m][n] = f32x4{0.f, 0.f, 0.f, 0.f};
    }
  float sreg[4];

  for (int kt = 0; kt < K_DIM / BK; ++kt) {
    const int k0 = kt * BK;
#pragma unroll
    for (int i = 0; i < 4; ++i) {
      const int chunk = i * 256 + t;
      const int r = chunk >> 3, c = chunk & 7;
      const int sw = ((c ^ (r & 7)) * 8);
      const f32x4* asrc = reinterpret_cast<const f32x4*>(x + (size_t)(rowBase + r) * K_DIM + k0 + c * 8);
      f32x4 f0 = asrc[0], f1 = asrc[1];
      u16x8 hv, lv;
#pragma unroll
      for (int j = 0; j < 8; ++j) {
        float f = (j < 4) ? f0[j] : f1[j - 4];
        unsigned u = __builtin_bit_cast(unsigned, f);
        unsigned hb = u & 0xffff0000u;
        float flo = f - __builtin_bit_cast(float, hb);
        unsigned lb = __builtin_bit_cast(unsigned, flo);
        hv[j] = (unsigned short)(hb >> 16);
        lv[j] = (unsigned short)(lb >> 16);
      }
      *reinterpret_cast<u16x8*>(&sAhi[r * BK + sw]) = hv;
      *reinterpret_cast<u16x8*>(&sAlo[r * BK + sw]) = lv;
      const i32x4* bsrc = reinterpret_cast<const i32x4*>(tern + (size_t)(colBase + r) * K_DIM + k0 + c * 8);
      i32x4 b0 = bsrc[0], b1 = bsrc[1];
      u16x8 bv;
#pragma unroll
      for (int j = 0; j < 8; ++j) {
        int v = (j < 4) ? b0[j] : b1[j - 4];
        unsigned bits = ((v & 1) ? 0x3F80u : 0u) | (((unsigned)(v >> 16)) & 0x8000u);
        bv[j] = (unsigned short)bits;
      }
      *reinterpret_cast<u16x8*>(&sB[r * BK + sw]) = bv;
    }
    if (!(kt & 1)) {
      const int g = kt >> 1;
#pragma unroll
      for (int n = 0; n < 4; ++n) {
        const int col = colBase + wc * 64 + n * 16 + lr;
        sreg[n] = scales[col * 32 + g];
      }
    }
    __syncthreads();
#pragma unroll
    for (int ks = 0; ks < 2; ++ks) {
      bf16x8 bfr[4], ah[4], al[4];
#pragma unroll
      for (int n = 0; n < 4; ++n) {
        const int row = wc * 64 + n * 16 + lr;
        const int addr = row * BK + (((ks * 4 + lk) ^ (row & 7)) * 8);
        bfr[n] = *reinterpret_cast<const bf16x8*>(&sB[addr]);
      }
#pragma unroll
      for (int m = 0; m < 4; ++m) {
        const int row = wr * 64 + m * 16 + lr;
        const int addr = row * BK + (((ks * 4 + lk) ^ (row & 7)) * 8);
        ah[m] = *reinterpret_cast<const bf16x8*>(&sAhi[addr]);
        al[m] = *reinterpret_cast<const bf16x8*>(&sAlo[addr]);
      }
#pragma unroll
      for (int m = 0; m < 4; ++m)
#pragma unroll
        for (int n = 0; n < 4; ++n) {
          gacc[m][n] = __builtin_amdgcn_mfma_f32_16x16x32_bf16(ah[m], bfr[n], gacc[m][n], 0, 0, 0);
          gacc[m][n] = __builtin_amdgcn_mfma_f32_16x16x32_bf16(al[m], bfr[n], gacc[m][n], 0, 0, 0);
        }
    }
    if (kt & 1) {
#pragma unroll
      for (int m = 0; m < 4; ++m)
#pragma unroll
        for (int n = 0; n < 4; ++n) {
          acc[m][n] += gacc[m][n] * sreg[n];
          gacc[m][n] = f32x4{0.f, 0.f, 0.f, 0.f};
        }
    }
    __syncthreads();
  }
#pragma unroll
  for (int m = 0; m < 4; ++m)
#pragma unroll
    for (int n = 0; n < 4; ++n) {
      const int col = colBase + wc * 64 + n * 16 + lr;
#pragma unroll
      for (int j = 0; j < 4; ++j) {
        const int row = rowBase + wr * 64 + m * 16 + lk * 4 + j;
        out[(size_t)row * N_DIM + col] = acc[m][n][j];
      }
    }
}

extern "C" void kernel_launch(void* const* d_in, const int* in_sizes, int n_in,
                              void* d_out, int out_size, void* d_ws, size_t ws_size,
                              hipStream_t stream) {
  const float* x      = (const float*)d_in[0];
  const int*   tern   = (const int*)d_in[1];
  const float* scales = (const float*)d_in[2];
  float* out          = (float*)d_out;

  if (ws_size >= WS_NEED) {
    _Float16* xh = (_Float16*)d_ws;
    _Float16* wh = xh + XH_ELEMS;
    xcvt<<<dim3(XH_ELEMS / (256 * 8)), dim3(256), 0, stream>>>(x, xh);
    wcvt<<<dim3(WH_ELEMS / (256 * 8)), dim3(256), 0, stream>>>(tern, scales, wh);
    flip_gemm_f16<<<dim3(GRID_M * GRID_N), dim3(256), 0, stream>>>(xh, wh, out);
  } else {
    flip_gemm_fb<<<dim3(GRID_M * GRID_N), dim3(256), 0, stream>>>(x, tern, scales, out);
  }
}

// Round 6
// 507.569 us; speedup vs baseline: 1.7526x; 1.0150x over previous
//
#include <hip/hip_runtime.h>
#include <hip/hip_bf16.h>
#include <hip/hip_fp16.h>
#include <cstdint>

// FlipLinear: out[M,N] = x[M,K] @ W[N,K]^T, W = ternary * scales[group].
// M=8192, N=4096, K=4096.
//
// R5: 256x256 8-phase pipelined fp16 GEMM (T2+T3+T4+T5), plain-HIP port of the
// m201 schedule. Precompute (R4-verified): xh=fp16(x), wh=fp16(ternary*scale).
//
// Schedule derivation (race-free by construction):
//  - LDS [buf][ks][256][32] fp16: each K-half (16KB) is a contiguous
//    global_load_lds target. Swizzle c4' = c4 ^ ((row>>1)&3): quarter-wave
//    granule map g = 4e + (lk ^ (p&3)) covers 8 granule groups, worst 2-way
//    (free per m136).
//  - 2 K-tiles/iter, 8 phases. Phase = {ds_read frags | stage 1 half | fence?
//    | barrier | 16 MFMA (setprio 1) | barrier}.
//  - Compute order (ks-major): p1..p4 = tile0 (mh0ks0,mh1ks0,mh0ks1,mh1ks1)
//    from buf0; p5..p8 = tile1 from buf1. B-frags read at mh0, reused at mh1.
//  - Stage order: p1: t(2it+1).Ak1->buf1 | p2-p5: t(2it+2).{Bk0,Ak0,Bk1,Ak1}
//    ->buf0 | p6-p8: t(2it+3).{Bk0,Ak0,Bk1}->buf1. Each half staged exactly
//    one phase after its previous copy's last ds_read; the reader phase's
//    trailing barrier (post-MFMA, lgkmcnt-gated) proves all waves consumed it.
//    vmcnt(6) at p4 => stages <= t(2it+1).Ak1 landed (covers p5-p8 readers);
//    vmcnt(6) at p8 => stages <= t(2it+2).Ak1 landed (covers next p1-p4).
//    Tail iteration: p4 uses vmcnt(0).

using f16x8  = __attribute__((ext_vector_type(8))) _Float16;
using f32x4  = __attribute__((ext_vector_type(4))) float;
using i32x4  = __attribute__((ext_vector_type(4))) int;

constexpr int M_DIM = 8192;
constexpr int N_DIM = 4096;
constexpr int K_DIM = 4096;
constexpr int BM = 256, BN = 256, BK = 64;
constexpr int GRID_N = N_DIM / BN;   // 16
constexpr int GRID_M = M_DIM / BM;   // 32
constexpr int NIT    = K_DIM / (2 * BK);  // 32 iterations, 2 K-tiles each

constexpr size_t XH_ELEMS = (size_t)M_DIM * K_DIM;
constexpr size_t WH_ELEMS = (size_t)N_DIM * K_DIM;
constexpr size_t WS_NEED  = (XH_ELEMS + WH_ELEMS) * 2;

// ---------------------------------------------------------------- precompute
__global__ __launch_bounds__(256)
void xcvt(const float* __restrict__ x, _Float16* __restrict__ xh) {
  const size_t idx = (size_t)blockIdx.x * 256 + threadIdx.x;
  const f32x4* src = reinterpret_cast<const f32x4*>(x) + idx * 2;
  f32x4 a = src[0], b = src[1];
  f16x8 h;
#pragma unroll
  for (int j = 0; j < 8; ++j) h[j] = (_Float16)((j < 4) ? a[j] : b[j - 4]);
  reinterpret_cast<f16x8*>(xh)[idx] = h;
}

__global__ __launch_bounds__(256)
void wcvt(const int* __restrict__ tern, const float* __restrict__ scales,
          _Float16* __restrict__ wh) {
  const size_t idx = (size_t)blockIdx.x * 256 + threadIdx.x;
  const float s = scales[idx >> 4];
  const i32x4* src = reinterpret_cast<const i32x4*>(tern) + idx * 2;
  i32x4 a = src[0], b = src[1];
  f16x8 h;
#pragma unroll
  for (int j = 0; j < 8; ++j) {
    int v = (j < 4) ? a[j] : b[j - 4];
    h[j] = (_Float16)(s * (float)v);
  }
  reinterpret_cast<f16x8*>(wh)[idx] = h;
}

// ---------------------------------------------------------------- main GEMM
#define FENCE6 asm volatile("s_waitcnt vmcnt(6)" ::: "memory")
#define FENCE0 asm volatile("s_waitcnt vmcnt(0)" ::: "memory")

__global__ __launch_bounds__(512, 2)
void flip_gemm_8ph(const _Float16* __restrict__ xh, const _Float16* __restrict__ wh,
                   float* __restrict__ out) {
  // 128 KiB LDS: [buf][ks][row][swizzled col], 16KB per (buf,ks) plane.
  __shared__ __align__(16) _Float16 sA[2][2][256][32];
  __shared__ __align__(16) _Float16 sB[2][2][256][32];

  const int t    = threadIdx.x;            // 0..511
  const int bid  = blockIdx.x;
  const int bn   = bid & (GRID_N - 1);
  const int bm   = bid >> 4;
  const int rowBase = bm * BM;
  const int colBase = bn * BN;

  const int wid  = t >> 6;                 // 0..7
  const int lane = t & 63;
  const int wm   = wid >> 2;               // 2 M-waves
  const int wn   = wid & 3;                // 4 N-waves
  const int lr   = lane & 15;
  const int lk   = lane >> 4;              // 0..3

  f32x4 acc[8][4];
#pragma unroll
  for (int m = 0; m < 8; ++m)
#pragma unroll
    for (int n = 0; n < 4; ++n) acc[m][n] = f32x4{0.f, 0.f, 0.f, 0.f};

  // stage one K-half (256 rows x 32 kcols = 16KB) of tile kt into ldsBase.
  // Linear LDS dest (wave-uniform base + lane*16); the swizzle lives in the
  // per-lane GLOBAL source address (inverse == forward XOR involution).
  auto stage_half = [&](const _Float16* __restrict__ src, _Float16* ldsBase,
                        int gRowBase, int kt, int ks) {
#pragma unroll
    for (int i = 0; i < 2; ++i) {
      const int q0  = i * 512 + wid * 64;        // wave-uniform chunk base
      const int q   = q0 + lane;                 // chunk in [0,1024)
      const int row = q >> 2;
      const int c4  = (q & 3) ^ ((row >> 1) & 3);
      const _Float16* g = src + (size_t)(gRowBase + row) * K_DIM + kt * 64 + ks * 32 + c4 * 8;
      __builtin_amdgcn_global_load_lds(
          (const __attribute__((address_space(1))) unsigned int*)g,
          (__attribute__((address_space(3))) unsigned int*)(ldsBase + q0 * 8), 16, 0, 0);
    }
  };

#define PHASE(MH, KS, RB, READB, STAGE_STMT, FENCE_STMT)                              \
  do {                                                                                \
    f16x8 Af[4];                                                                      \
    if (READB) {                                                                      \
      _Pragma("unroll") for (int fn = 0; fn < 4; ++fn) {                              \
        const int row = wn * 64 + fn * 16 + lr;                                       \
        Bfrag[fn] = *reinterpret_cast<const f16x8*>(                                  \
            &sB[RB][KS][row][(lk ^ ((row >> 1) & 3)) * 8]);                           \
      }                                                                               \
    }                                                                                 \
    _Pragma("unroll") for (int fm = 0; fm < 4; ++fm) {                                \
      const int row = wm * 128 + MH * 64 + fm * 16 + lr;                              \
      Af[fm] = *reinterpret_cast<const f16x8*>(                                       \
          &sA[RB][KS][row][(lk ^ ((row >> 1) & 3)) * 8]);                             \
    }                                                                                 \
    STAGE_STMT;                                                                       \
    FENCE_STMT;                                                                       \
    __builtin_amdgcn_s_barrier();                                                     \
    __builtin_amdgcn_s_setprio(1);                                                    \
    _Pragma("unroll") for (int fm = 0; fm < 4; ++fm)                                  \
      _Pragma("unroll") for (int fn = 0; fn < 4; ++fn)                                \
        acc[MH * 4 + fm][fn] = __builtin_amdgcn_mfma_f32_16x16x32_f16(                \
            Af[fm], Bfrag[fn], acc[MH * 4 + fm][fn], 0, 0, 0);                        \
    __builtin_amdgcn_s_setprio(0);                                                    \
    __builtin_amdgcn_s_barrier();                                                     \
  } while (0)

  // Prologue: tile0 fully + tile1 first 3 halves; vmcnt(6) => tile0 landed.
  stage_half(wh, &sB[0][0][0][0], colBase, 0, 0);
  stage_half(xh, &sA[0][0][0][0], rowBase, 0, 0);
  stage_half(wh, &sB[0][1][0][0], colBase, 0, 1);
  stage_half(xh, &sA[0][1][0][0], rowBase, 0, 1);
  stage_half(wh, &sB[1][0][0][0], colBase, 1, 0);
  stage_half(xh, &sA[1][0][0][0], rowBase, 1, 0);
  stage_half(wh, &sB[1][1][0][0], colBase, 1, 1);
  FENCE6;
  __builtin_amdgcn_s_barrier();

  f16x8 Bfrag[4];
  for (int it = 0; it < NIT; ++it) {
    const int t2 = 2 * it + 2;           // next even tile -> buf0
    const int t3 = 2 * it + 3;           // next odd tile  -> buf1
    const bool st = (it < NIT - 1);

    // p1: compute buf0 (mh0,ks0); stage current odd tile's Ak1 -> buf1
    PHASE(0, 0, 0, true,  { stage_half(xh, &sA[1][1][0][0], rowBase, 2 * it + 1, 1); }, {});
    // p2: compute buf0 (mh1,ks0, B reuse); stage t2.Bk0 -> buf0
    PHASE(1, 0, 0, false, { if (st) stage_half(wh, &sB[0][0][0][0], colBase, t2, 0); }, {});
    // p3: compute buf0 (mh0,ks1); stage t2.Ak0 -> buf0
    PHASE(0, 1, 0, true,  { if (st) stage_half(xh, &sA[0][0][0][0], rowBase, t2, 0); }, {});
    // p4: compute buf0 (mh1,ks1); stage t2.Bk1 -> buf0; FENCE
    PHASE(1, 1, 0, false, { if (st) stage_half(wh, &sB[0][1][0][0], colBase, t2, 1); },
          { if (st) { FENCE6; } else { FENCE0; } });
    // p5: compute buf1 (mh0,ks0); stage t2.Ak1 -> buf0
    PHASE(0, 0, 1, true,  { if (st) stage_half(xh, &sA[0][1][0][0], rowBase, t2, 1); }, {});
    // p6: compute buf1 (mh1,ks0, B reuse); stage t3.Bk0 -> buf1
    PHASE(1, 0, 1, false, { if (st) stage_half(wh, &sB[1][0][0][0], colBase, t3, 0); }, {});
    // p7: compute buf1 (mh0,ks1); stage t3.Ak0 -> buf1
    PHASE(0, 1, 1, true,  { if (st) stage_half(xh, &sA[1][0][0][0], rowBase, t3, 0); }, {});
    // p8: compute buf1 (mh1,ks1); stage t3.Bk1 -> buf1; FENCE
    PHASE(1, 1, 1, false, { if (st) stage_half(wh, &sB[1][1][0][0], colBase, t3, 1); },
          { if (st) { FENCE6; } });
  }

  // Epilogue: C layout col = lane&15, row = (lane>>4)*4 + j (R1/R4-verified).
#pragma unroll
  for (int mf = 0; mf < 8; ++mf)
#pragma unroll
    for (int fn = 0; fn < 4; ++fn) {
      const int col = colBase + wn * 64 + fn * 16 + lr;
#pragma unroll
      for (int j = 0; j < 4; ++j) {
        const int row = rowBase + wm * 128 + mf * 16 + lk * 4 + j;
        out[(size_t)row * N_DIM + col] = acc[mf][fn][j];
      }
    }
}

extern "C" void kernel_launch(void* const* d_in, const int* in_sizes, int n_in,
                              void* d_out, int out_size, void* d_ws, size_t ws_size,
                              hipStream_t stream) {
  const float* x      = (const float*)d_in[0];
  const int*   tern   = (const int*)d_in[1];
  const float* scales = (const float*)d_in[2];
  float* out          = (float*)d_out;

  _Float16* xh = (_Float16*)d_ws;
  _Float16* wh = xh + XH_ELEMS;
  xcvt<<<dim3(XH_ELEMS / (256 * 8)), dim3(256), 0, stream>>>(x, xh);
  wcvt<<<dim3(WH_ELEMS / (256 * 8)), dim3(256), 0, stream>>>(tern, scales, wh);
  flip_gemm_8ph<<<dim3(GRID_M * GRID_N), dim3(512), 0, stream>>>(xh, wh, out);
  (void)ws_size; (void)in_sizes; (void)n_in; (void)out_size;
}